// Round 9
// baseline (312.180 us; speedup 1.0000x reference)
//
#include <hip/hip_runtime.h>
#include <math.h>

#define BTOT 16384

typedef __attribute__((ext_vector_type(8))) short s16x8;
typedef __attribute__((ext_vector_type(4))) float f32x4;
typedef __attribute__((ext_vector_type(4))) uint u32x4;
typedef __attribute__((ext_vector_type(2))) float f32x2;
typedef __attribute__((ext_vector_type(2))) uint u32x2;

// U region offsets (in ushorts).
// L0-L3: two-stage layout. Per-node blob: [din*256 hi][din*256 lo] ushorts,
//   frag[nt][l32][jj] = W[i=(l32>>4)*8+jj][j=nt][d=l32&15]   (i>=din -> 0)
// L0 node stride padded 4608->6144 ushorts (12 KB) = 3 x 4KB DMA sweeps.
// L4-L7: OLD direct-bilinear layout (back kernel unchanged).
#define NOFF0 0u         // 128 x 6144
#define NOFF1 786432u    // 64 x 8192
#define NOFF2 1310720u   // 32 x 8192
#define NOFF3 1572864u   // 16 x 8192
#define OFF4  1703936u   // 8 x 8192 (old layout)
#define OFF5  1769472u   // 4 x 8192
#define OFF6  1802240u   // 2 x 8192
#define OFF7  1818624u   // 1 x 8192  (end = 1826816 ushorts = 3.65 MB < 4 MB)

__device__ __forceinline__ ushort rtn_bf16(float x) {
  uint u = __builtin_bit_cast(uint, x);
  uint r = u + 0x7fffu + ((u >> 16) & 1u);
  return (ushort)(r >> 16);
}

// ---------------- W-frag prep: LDS-staged coalesced reads ----------------------
__global__ __launch_bounds__(256) void wprep_kernel(
    const float* __restrict__ W0, const float* __restrict__ W1,
    const float* __restrict__ W2, const float* __restrict__ W3,
    const float* __restrict__ W4, const float* __restrict__ W5,
    const float* __restrict__ W6, const float* __restrict__ W7,
    ushort* __restrict__ U) {
  __shared__ float WL[4096];
  int blk = blockIdx.x;
  if (blk < 240) {
    // -------- two-stage layout for L0..L3 --------
    const float* Wsrc; ushort* dst; int din, nsrc;
    if (blk < 128)      { Wsrc = W0 + blk * 1296;         dst = U + NOFF0 + (size_t)blk * 6144;         din = 9;  nsrc = 1296; }
    else if (blk < 192) { Wsrc = W1 + (blk - 128) * 4096; dst = U + NOFF1 + (size_t)(blk - 128) * 8192; din = 16; nsrc = 4096; }
    else if (blk < 224) { Wsrc = W2 + (blk - 192) * 4096; dst = U + NOFF2 + (size_t)(blk - 192) * 8192; din = 16; nsrc = 4096; }
    else                { Wsrc = W3 + (blk - 224) * 4096; dst = U + NOFF3 + (size_t)(blk - 224) * 8192; din = 16; nsrc = 4096; }
    for (int i = threadIdx.x; i < nsrc; i += 256) WL[i] = Wsrc[i];   // coalesced
    __syncthreads();
    int entries = din * 256;   // per half (hi / lo)
    for (int e = threadIdx.x; e < entries; e += 256) {
      int nt = e >> 8, l32 = (e >> 3) & 31, jj = e & 7;
      int i = ((l32 >> 4) << 3) + jj, d = l32 & 15;
      float w = (i < din) ? WL[(i * din + nt) * 16 + d] : 0.f;
      uint u = __builtin_bit_cast(uint, w);
      uint h = u & 0xffff0000u;
      dst[e] = (ushort)(h >> 16);
      dst[entries + e] = rtn_bf16(w - __builtin_bit_cast(float, h));
    }
  } else {
    // -------- old direct-bilinear layout for L4..L7 --------
    const float* Wsrc; ushort* dst; int nsrc; bool dout1 = false;
    if (blk < 248)      { Wsrc = W4 + (blk - 240) * 4096; dst = U + OFF4 + (size_t)(blk - 240) * 8192; nsrc = 4096; }
    else if (blk < 252) { Wsrc = W5 + (blk - 248) * 4096; dst = U + OFF5 + (size_t)(blk - 248) * 8192; nsrc = 4096; }
    else if (blk < 254) { Wsrc = W6 + (blk - 252) * 4096; dst = U + OFF6 + (size_t)(blk - 252) * 8192; nsrc = 4096; }
    else                { Wsrc = W7;                      dst = U + OFF7;                              nsrc = 256; dout1 = true; }
    for (int i = threadIdx.x; i < nsrc; i += 256) WL[i] = Wsrc[i];
    __syncthreads();
    const int entries = 8 * 512;
    for (int e = threadIdx.x; e < entries; e += 256) {
      int kt = e >> 9, l = (e >> 3) & 63, jv = e & 7;
      int k = kt * 32 + ((l >> 4) << 3) + jv;
      int i = k >> 4, j = k & 15, n = l & 15;
      float w;
      if (dout1) w = (n == 0) ? WL[i * 16 + j] : 0.f;
      else       w = WL[(i * 16 + j) * 16 + n];
      uint u = __builtin_bit_cast(uint, w);
      uint h = u & 0xffff0000u;
      dst[e] = (ushort)(h >> 16);
      dst[entries + e] = rtn_bf16(w - __builtin_bit_cast(float, h));
    }
  }
}

// ---- OLD split + 3 MFMAs per K-tile (kept for the back kernel) ----------------
__device__ __forceinline__ f32x4 split3(float li, const f32x2* rf2,
                                        s16x8 wh, s16x8 wl, f32x4 acc) {
  const f32x2 li2 = {li, li};
  u32x4 hv, lv;
#pragma unroll
  for (int jp = 0; jp < 4; ++jp) {
    f32x2 p2 = li2 * rf2[jp];
    u32x2 u2 = __builtin_bit_cast(u32x2, p2);
    u32x2 hb = u2 & 0xffff0000u;
    f32x2 h2 = __builtin_bit_cast(f32x2, hb);
    f32x2 q2 = __builtin_elementwise_fma(li2, rf2[jp], -h2);
    u32x2 uq = __builtin_bit_cast(u32x2, q2);
    hv[jp] = __builtin_amdgcn_perm(u2.y, u2.x, 0x07060302u);
    lv[jp] = __builtin_amdgcn_perm(uq.y, uq.x, 0x07060302u);
  }
  s16x8 ahi = __builtin_bit_cast(s16x8, hv);
  s16x8 alo = __builtin_bit_cast(s16x8, lv);
  acc = __builtin_amdgcn_mfma_f32_16x16x32_bf16(ahi, wh, acc, 0, 0, 0);
  acc = __builtin_amdgcn_mfma_f32_16x16x32_bf16(alo, wh, acc, 0, 0, 0);
  acc = __builtin_amdgcn_mfma_f32_16x16x32_bf16(ahi, wl, acc, 0, 0, 0);
  return acc;
}

template <int KTN, bool L0M>
__device__ __forceinline__ f32x4 mfma_core(const float* Lcol, const float* Rcol,
                                           const int ld, const ushort* __restrict__ Wf,
                                           int lane) {
  const int g = lane >> 4;
  const int j0 = (g & 1) * 8, gh = g >> 1;
  const float* Lg = Lcol + gh * ld;
  float lf[KTN];
#pragma unroll
  for (int i = 0; i < KTN; ++i)
    lf[i] = (L0M && (2 * i + gh > 8)) ? 0.f : Lg[2 * i * ld];
  f32x2 rf2[4];
#pragma unroll
  for (int j = 0; j < 8; ++j) {
    float v = (L0M && (j0 + j >= 9)) ? 0.f : Rcol[(j0 + j) * ld];
    rf2[j >> 1][j & 1] = v;
  }
  f32x4 acc = {0.f, 0.f, 0.f, 0.f};
  const int entries = KTN * 512;
#pragma unroll
  for (int kt = 0; kt < KTN; ++kt) {
    const s16x8 wh = *(const s16x8*)&Wf[(kt * 64 + lane) * 8];
    const s16x8 wl = *(const s16x8*)&Wf[entries + (kt * 64 + lane) * 8];
    acc = split3(lf[kt], rf2, wh, wl, acc);
  }
  return acc;
}

// ================= Two-stage core (levels 0-3), W from LDS, 2 row-tiles ========
// Stage 1 (MFMA): T[b,(j,d)] = sum_i l[b,i] * W[i,(j,d)], K=32 packs [l_hi;l_lo].
// Stage 2 (VALU): o[b,d] = sum_j r[b,j] * T[b,j,d] -- 4 v_fmac per tile.
// Each wave owns 32 batch rows (2 row-tiles) so every wh/wl ds_read_b128 feeds
// TWO MFMAs -- halves the W LDS-port traffic that R6 PMC showed dominates
// (~75us of 170us was W-fragment ds_reads at 1 read per 16-row MFMA).
#define LDB 20   // b-major buffer stride: 80B rows -> 16B-aligned, 2-way banks (free)

__device__ __forceinline__ void feats_row(float xv, float* Fr) {
  float s1 = __sinf(xv), c1 = __cosf(xv);
  float s2 = s1 * c1 + c1 * s1, c2 = c1 * c1 - s1 * s1;
  float s3 = s1 * c2 + c1 * s2, c3 = c1 * c2 - s1 * s2;
  float s4 = s1 * c3 + c1 * s3, c4 = c1 * c3 - s1 * s3;
  f32x4 v0 = {1.f, s1, s2, s3};
  f32x4 v1 = {s4, c1, c2, c3};
  *(f32x4*)(Fr) = v0;
  *(f32x4*)(Fr + 4) = v1;
  Fr[8] = c4;
}

// Build bf16 A-frag from 16 f32: g<2 -> hi halves, g>=2 -> lo residuals.
__device__ __forceinline__ s16x8 build_a(const float* lp, int g) {
  f32x4 v0 = *(const f32x4*)lp;
  f32x4 v1 = *(const f32x4*)(lp + 4);
  u32x4 u0 = __builtin_bit_cast(u32x4, v0);
  u32x4 u1 = __builtin_bit_cast(u32x4, v1);
  u32x4 hv;
  if (g < 2) {
    hv[0] = __builtin_amdgcn_perm(u0.y, u0.x, 0x07060302u);
    hv[1] = __builtin_amdgcn_perm(u0.w, u0.z, 0x07060302u);
    hv[2] = __builtin_amdgcn_perm(u1.y, u1.x, 0x07060302u);
    hv[3] = __builtin_amdgcn_perm(u1.w, u1.z, 0x07060302u);
  } else {
    u32x4 h0 = u0 & 0xffff0000u, h1 = u1 & 0xffff0000u;
    f32x4 q0 = v0 - __builtin_bit_cast(f32x4, h0);
    f32x4 q1 = v1 - __builtin_bit_cast(f32x4, h1);
    u32x4 w0 = __builtin_bit_cast(u32x4, q0), w1 = __builtin_bit_cast(u32x4, q1);
    hv[0] = __builtin_amdgcn_perm(w0.y, w0.x, 0x07060302u);
    hv[1] = __builtin_amdgcn_perm(w0.w, w0.z, 0x07060302u);
    hv[2] = __builtin_amdgcn_perm(w1.y, w1.x, 0x07060302u);
    hv[3] = __builtin_amdgcn_perm(w1.w, w1.z, 0x07060302u);
  }
  return __builtin_bit_cast(s16x8, hv);
}

template <int NT>
__device__ __forceinline__ void core2L2(const float* Lb, const float* Rb,
                                        const ushort* Wl, int lane,
                                        f32x4& o1, f32x4& o2) {
  const int bb = lane & 15, g = lane >> 4;
  const ushort* whp = Wl + (lane & 31) * 8;   // lanes 32-63 broadcast (free)

  // A-frags for row-tile 0 (rows 0-15) and row-tile 1 (rows 16-31)
  s16x8 a1 = build_a(Lb + bb * LDB + (g & 1) * 8, g);
  s16x8 a2 = build_a(Lb + (16 + bb) * LDB + (g & 1) * 8, g);

  const float* rp1 = Rb + (g * 4) * LDB;        // rv rows b = g*4..+3 (bcast)
  const float* rp2 = Rb + (16 + g * 4) * LDB;   // tile-1 rows
  o1 = (f32x4){0.f, 0.f, 0.f, 0.f};
  o2 = (f32x4){0.f, 0.f, 0.f, 0.f};
  const f32x4 zz = {0.f, 0.f, 0.f, 0.f};
#pragma unroll
  for (int c = 0; c < (NT + 3) >> 2; ++c) {
    f32x4 ra0 = *(const f32x4*)(rp1 + c * 4);
    f32x4 ra1 = *(const f32x4*)(rp1 + LDB + c * 4);
    f32x4 ra2 = *(const f32x4*)(rp1 + 2 * LDB + c * 4);
    f32x4 ra3 = *(const f32x4*)(rp1 + 3 * LDB + c * 4);
    f32x4 rb0 = *(const f32x4*)(rp2 + c * 4);
    f32x4 rb1 = *(const f32x4*)(rp2 + LDB + c * 4);
    f32x4 rb2 = *(const f32x4*)(rp2 + 2 * LDB + c * 4);
    f32x4 rb3 = *(const f32x4*)(rp2 + 3 * LDB + c * 4);
#pragma unroll
    for (int jj = 0; jj < 4; ++jj) {
      const int nt = c * 4 + jj;
      if (nt < NT) {
        s16x8 wh = *(const s16x8*)(whp + nt * 256);          // read ONCE,
        s16x8 wl = *(const s16x8*)(whp + (NT + nt) * 256);   // feeds 4 MFMAs
        f32x4 t1 = __builtin_amdgcn_mfma_f32_16x16x32_bf16(a1, wh, zz, 0, 0, 0);
        t1 = __builtin_amdgcn_mfma_f32_16x16x32_bf16(a1, wl, t1, 0, 0, 0);
        f32x4 t2 = __builtin_amdgcn_mfma_f32_16x16x32_bf16(a2, wh, zz, 0, 0, 0);
        t2 = __builtin_amdgcn_mfma_f32_16x16x32_bf16(a2, wl, t2, 0, 0, 0);
        o1[0] += ra0[jj] * t1[0];
        o1[1] += ra1[jj] * t1[1];
        o1[2] += ra2[jj] * t1[2];
        o1[3] += ra3[jj] * t1[3];
        o2[0] += rb0[jj] * t2[0];
        o2[1] += rb1[jj] * t2[1];
        o2[2] += rb2[jj] * t2[2];
        o2[3] += rb3[jj] * t2[3];
      }
    }
  }
  // o1[r] = out[b=g*4+r][d=lane&15], o2[r] = out[b=16+g*4+r][d=lane&15]
}

// Async DMA: stage one W item (12 or 16 KB) into LDS. Wave w covers bytes
// [c*4096 + w*1024, +1024) of each 4 KB sweep.
__device__ __forceinline__ void stage_item(const ushort* gsrc, ushort* ldst,
                                           int w, int lane, int nchunks) {
#pragma unroll
  for (int c = 0; c < 4; ++c) {
    if (c < nchunks) {
      const int off = c * 4096 + w * 1024;
      __builtin_amdgcn_global_load_lds(
          (const __attribute__((address_space(1))) unsigned int*)((const char*)gsrc + off + lane * 16),
          (__attribute__((address_space(3))) unsigned int*)((char*)ldst + off),
          16, 0, 0);
    }
  }
}

// Flat per-block item schedule (15 items), dependency-ordered.
constexpr int LVL15[15] = {0,0,1,0,0,1,2,0,0,1,0,0,1,2,3};
constexpr int SUB15[15] = {0,1,0,2,3,1,0,4,5,2,6,7,3,1,0};

// ---------------- Levels 0-3 fused, two-stage, DMA-pipelined W -----------------
// 128 rows/block (4 waves x 32 rows, 2 row-tiles each). LDS 120 KB -> 1 block/CU
// (>64KB static proven at R6's 76KB). Counted vmcnt (never 0 mid-loop) + raw
// s_barrier keep item k+1's DMA in flight across item k's compute.
__global__ __launch_bounds__(256, 1) void ttn_front_kernel(
    const float* __restrict__ x, const float* __restrict__ fminp,
    const ushort* __restrict__ U, float* __restrict__ s1out) {
  __shared__ float S[4][8][32 * LDB];   // 80 KB: per-wave F0,F1,A0,B0,A1,B1,A2,B2
  __shared__ ushort WS[2][8192];        // 32 KB: W double-buffer (block-shared)
  __shared__ float XB[4][64][8];        // 8 KB: pre-staged x scalars

  const int tid = threadIdx.x;
  const int lane = tid & 63, w = tid >> 6;
  const int m = lane & 15, g = lane >> 4;
  const int row32 = lane & 31, side = lane >> 5;   // feats mapping (all 64 lanes)
  const int b0 = blockIdx.x * 128;
  const int s = blockIdx.y;
  const float fmin = fminp[0];

  float* F0 = S[w][0]; float* F1 = S[w][1];
  float* A0 = S[w][2]; float* B0 = S[w][3];
  float* A1 = S[w][4]; float* B1 = S[w][5];
  float* A2 = S[w][6]; float* B2 = S[w][7];

  // zero feat cols 9..15 for all 32 rows of both F-buffers (A-frag reads them)
  {
    float* Fz = side ? F1 : F0;
    Fz[row32 * LDB + 9] = 0.f; Fz[row32 * LDB + 10] = 0.f; Fz[row32 * LDB + 11] = 0.f;
    *(f32x4*)(Fz + row32 * LDB + 12) = (f32x4){0.f, 0.f, 0.f, 0.f};
  }
  // pre-stage x: lane covers (row=lane&31, side=lane>>5); 8 L0 items -> 8 scalars
  {
    const float* xrow = x + (size_t)(b0 + w * 32 + row32) * 256 + s * 16;
#pragma unroll
    for (int i = 0; i < 8; ++i) XB[w][lane][i] = xrow[2 * i + side];
  }

  float* outG = s1out + (size_t)(s * 16) * BTOT + b0;

  auto storeO2 = [&](const f32x4& a1v, const f32x4& a2v, float* Out) {
#pragma unroll
    for (int r = 0; r < 4; ++r) Out[(g * 4 + r) * LDB + m] = a1v[r];
#pragma unroll
    for (int r = 0; r < 4; ++r) Out[(16 + g * 4 + r) * LDB + m] = a2v[r];
  };
  auto goff = [&](int kk) -> const ushort* {
    const int l2 = LVL15[kk], s2 = SUB15[kk];
    if (l2 == 0) return U + NOFF0 + (size_t)(8 * s + s2) * 6144;
    if (l2 == 1) return U + NOFF1 + (size_t)(4 * s + s2) * 8192;
    if (l2 == 2) return U + NOFF2 + (size_t)(2 * s + s2) * 8192;
    return U + NOFF3 + (size_t)s * 8192;
  };

  // prologue: items 0,1 in flight (both L0 -> 3 sweeps each)
  stage_item(goff(0), WS[0], w, lane, 3);
  stage_item(goff(1), WS[1], w, lane, 3);

#pragma unroll
  for (int k = 0; k < 15; ++k) {
    const int lvl = LVL15[k], sub = SUB15[k];
    // wait for item k only; item k+1's loads stay in flight (counted vmcnt)
    const int wn = (k < 14) ? (LVL15[k + 1] == 0 ? 3 : 4) : 0;
    if (wn == 3)      asm volatile("s_waitcnt vmcnt(3)" ::: "memory");
    else if (wn == 4) asm volatile("s_waitcnt vmcnt(4)" ::: "memory");
    else              asm volatile("s_waitcnt vmcnt(0)" ::: "memory");
    __builtin_amdgcn_s_barrier();
    const ushort* Wl = WS[k & 1];
    f32x4 o1, o2;
    if (lvl == 0) {
      feats_row(XB[w][lane][sub] * fmin, (side ? F1 : F0) + row32 * LDB);
      core2L2<9>(F0, F1, Wl, lane, o1, o2);
      storeO2(o1, o2, (sub & 1) ? B0 : A0);
    } else if (lvl == 1) {
      core2L2<16>(A0, B0, Wl, lane, o1, o2);
      storeO2(o1, o2, (sub & 1) ? B1 : A1);
    } else if (lvl == 2) {
      core2L2<16>(A1, B1, Wl, lane, o1, o2);
      storeO2(o1, o2, (sub & 1) ? B2 : A2);
    } else {
      core2L2<16>(A2, B2, Wl, lane, o1, o2);
#pragma unroll
      for (int r = 0; r < 4; ++r)
        outG[(size_t)m * BTOT + w * 32 + g * 4 + r] = o1[r];
#pragma unroll
      for (int r = 0; r < 4; ++r)
        outG[(size_t)m * BTOT + w * 32 + 16 + g * 4 + r] = o2[r];
    }
    __builtin_amdgcn_s_barrier();   // all waves done reading WS[k&1]
    if (k + 2 < 15)
      stage_item(goff(k + 2), WS[k & 1], w, lane, LVL15[k + 2] == 0 ? 3 : 4);
  }
}

// ---------------- Levels 4-7: tree-parallel, 8 waves / 16-b tile ---------------
// (unchanged; uses OLD U layout at OFF4..OFF7)
__global__ __launch_bounds__(512) void ttn_back_kernel(
    const float* __restrict__ s1, const ushort* __restrict__ U,
    float* __restrict__ out) {
  __shared__ float T[256 * 17];        // 17.4 KB
  __shared__ float P[8][16 * 17];      // 8.7 KB
  const int tid = threadIdx.x;
  const int lane = tid & 63, v = tid >> 6;   // v = 0..7
  const int m = lane & 15, g = lane >> 4;
  const int b0 = blockIdx.x * 16;

  auto storeC = [&](f32x4 a, float* Buf) {
#pragma unroll
    for (int r = 0; r < 4; ++r) Buf[m * 17 + g * 4 + r] = a[r];
  };

#pragma unroll
  for (int it = 0; it < 2; ++it) {     // stage [256 rows][16 b], coalesced float4
    int idx = it * 512 + tid;          // 0..1023
    int r = idx >> 2, c4 = (idx & 3) * 4;
    float4 vv = *(const float4*)&s1[(size_t)r * BTOT + b0 + c4];
    T[r * 17 + c4 + 0] = vv.x; T[r * 17 + c4 + 1] = vv.y;
    T[r * 17 + c4 + 2] = vv.z; T[r * 17 + c4 + 3] = vv.w;
  }
  __syncthreads();

  // L4 node v: rows 32v..+15 x 32v+16..+31 -> P[v]
  {
    f32x4 a = mfma_core<8, false>(&T[(32 * v) * 17 + m], &T[(32 * v + 16) * 17 + m],
                                  17, U + OFF4 + (size_t)v * 8192, lane);
    storeC(a, P[v]);
  }
  __syncthreads();

  if (v < 4) {  // L5 node v: P[2v] x P[2v+1] -> T region v (T dead)
    f32x4 a = mfma_core<8, false>(&P[2 * v][m], &P[2 * v + 1][m], 17,
                                  U + OFF5 + (size_t)v * 8192, lane);
    storeC(a, &T[v * 16 * 17]);
  }
  __syncthreads();

  if (v < 2) {  // L6 node v: Tq[2v] x Tq[2v+1] -> P[v] (P dead)
    f32x4 a = mfma_core<8, false>(&T[(2 * v) * 16 * 17 + m],
                                  &T[(2 * v + 1) * 16 * 17 + m], 17,
                                  U + OFF6 + (size_t)v * 8192, lane);
    storeC(a, P[v]);
  }
  __syncthreads();

  if (v == 0) { // L7: P[0] x P[1]; W7-frag nonzero only in d=0 column
    f32x4 a = mfma_core<8, false>(&P[0][m], &P[1][m], 17, U + OFF7, lane);
    if (m == 0) {
#pragma unroll
      for (int r = 0; r < 4; ++r) out[b0 + g * 4 + r] = a[r];
    }
  }
}

extern "C" void kernel_launch(void* const* d_in, const int* in_sizes, int n_in,
                              void* d_out, int out_size, void* d_ws, size_t ws_size,
                              hipStream_t stream) {
  const float* x    = (const float*)d_in[0];
  const float* fmin = (const float*)d_in[1];
  const float* W0   = (const float*)d_in[2];
  const float* W1   = (const float*)d_in[3];
  const float* W2   = (const float*)d_in[4];
  const float* W3   = (const float*)d_in[5];
  const float* W4   = (const float*)d_in[6];
  const float* W5   = (const float*)d_in[7];
  const float* W6   = (const float*)d_in[8];
  const float* W7   = (const float*)d_in[9];
  float* out = (float*)d_out;

  // ws: [0,4MB) W-frags U | [4MB,+16.8MB) s1
  ushort* U = (ushort*)d_ws;
  float* s1 = (float*)((char*)d_ws + (4u << 20));

  wprep_kernel<<<255, 256, 0, stream>>>(W0, W1, W2, W3, W4, W5, W6, W7, U);
  ttn_front_kernel<<<dim3(128, 16), 256, 0, stream>>>(x, fmin, U, s1);
  ttn_back_kernel<<<1024, 512, 0, stream>>>(s1, U, out);
}

// Round 13
// 235.359 us; speedup vs baseline: 1.3264x; 1.3264x over previous
//
#include <hip/hip_runtime.h>
#include <math.h>

#define BTOT 16384

typedef __attribute__((ext_vector_type(8))) short s16x8;
typedef __attribute__((ext_vector_type(4))) float f32x4;
typedef __attribute__((ext_vector_type(4))) uint u32x4;
typedef __attribute__((ext_vector_type(2))) float f32x2;
typedef __attribute__((ext_vector_type(2))) uint u32x2;

// U region offsets (in ushorts). Per-node blob: [KTN*512 hi][KTN*512 lo].
#define OFF0 0u          // W0: 128 nodes x 5120
#define OFF1 655360u     // W1: 64 x 8192
#define OFF2 1179648u    // W2: 32 x 8192
#define OFF3 1441792u    // W3: 16 x 8192
#define OFF4 1572864u    // W4: 8 x 8192
#define OFF5 1638400u    // W5: 4 x 8192
#define OFF6 1671168u    // W6: 2 x 8192
#define OFF7 1687552u    // W7: 1 x 8192

__device__ __forceinline__ ushort rtn_bf16(float x) {
  uint u = __builtin_bit_cast(uint, x);
  uint r = u + 0x7fffu + ((u >> 16) & 1u);
  return (ushort)(r >> 16);
}

// ---------------- W-frag prep: LDS-staged coalesced reads ----------------------
__global__ __launch_bounds__(256) void wprep_kernel(
    const float* __restrict__ W0, const float* __restrict__ W1,
    const float* __restrict__ W2, const float* __restrict__ W3,
    const float* __restrict__ W4, const float* __restrict__ W5,
    const float* __restrict__ W6, const float* __restrict__ W7,
    ushort* __restrict__ U) {
  __shared__ float WL[4096];
  int blk = blockIdx.x;
  const float* Wsrc; ushort* dst; int ktN, din, nsrc; bool dout1 = false;
  if (blk < 128)      { Wsrc = W0 + blk * 1296;         dst = U + OFF0 + (size_t)blk * 5120;         ktN = 5; din = 9;  nsrc = 1296; }
  else if (blk < 192) { Wsrc = W1 + (blk - 128) * 4096; dst = U + OFF1 + (size_t)(blk - 128) * 8192; ktN = 8; din = 16; nsrc = 4096; }
  else if (blk < 224) { Wsrc = W2 + (blk - 192) * 4096; dst = U + OFF2 + (size_t)(blk - 192) * 8192; ktN = 8; din = 16; nsrc = 4096; }
  else if (blk < 240) { Wsrc = W3 + (blk - 224) * 4096; dst = U + OFF3 + (size_t)(blk - 224) * 8192; ktN = 8; din = 16; nsrc = 4096; }
  else if (blk < 248) { Wsrc = W4 + (blk - 240) * 4096; dst = U + OFF4 + (size_t)(blk - 240) * 8192; ktN = 8; din = 16; nsrc = 4096; }
  else if (blk < 252) { Wsrc = W5 + (blk - 248) * 4096; dst = U + OFF5 + (size_t)(blk - 248) * 8192; ktN = 8; din = 16; nsrc = 4096; }
  else if (blk < 254) { Wsrc = W6 + (blk - 252) * 4096; dst = U + OFF6 + (size_t)(blk - 252) * 8192; ktN = 8; din = 16; nsrc = 4096; }
  else                { Wsrc = W7;                      dst = U + OFF7;                              ktN = 8; din = 16; nsrc = 256; dout1 = true; }
  for (int i = threadIdx.x; i < nsrc; i += 256) WL[i] = Wsrc[i];   // coalesced
  __syncthreads();
  int entries = ktN * 512;
  for (int e = threadIdx.x; e < entries; e += 256) {
    int kt = e >> 9, l = (e >> 3) & 63, jv = e & 7;
    int k = kt * 32 + ((l >> 4) << 3) + jv;
    int i = k >> 4, j = k & 15, n = l & 15;
    float w;
    if (dout1) w = (n == 0) ? WL[i * 16 + j] : 0.f;
    else       w = (i < din && j < din) ? WL[(i * din + j) * 16 + n] : 0.f;
    uint u = __builtin_bit_cast(uint, w);
    uint h = u & 0xffff0000u;
    dst[e] = (ushort)(h >> 16);
    dst[entries + e] = rtn_bf16(w - __builtin_bit_cast(float, h));
  }
}

// ---- split + 3 MFMAs for one 16-b tile, given resident wh/wl ------------------
__device__ __forceinline__ f32x4 split3(float li, const f32x2* rf2,
                                        s16x8 wh, s16x8 wl, f32x4 acc) {
  const f32x2 li2 = {li, li};
  u32x4 hv, lv;
#pragma unroll
  for (int jp = 0; jp < 4; ++jp) {
    f32x2 p2 = li2 * rf2[jp];
    u32x2 u2 = __builtin_bit_cast(u32x2, p2);
    u32x2 hb = u2 & 0xffff0000u;
    f32x2 h2 = __builtin_bit_cast(f32x2, hb);
    f32x2 q2 = __builtin_elementwise_fma(li2, rf2[jp], -h2);
    u32x2 uq = __builtin_bit_cast(u32x2, q2);
    hv[jp] = __builtin_amdgcn_perm(u2.y, u2.x, 0x07060302u);
    lv[jp] = __builtin_amdgcn_perm(uq.y, uq.x, 0x07060302u);
  }
  s16x8 ahi = __builtin_bit_cast(s16x8, hv);
  s16x8 alo = __builtin_bit_cast(s16x8, lv);
  acc = __builtin_amdgcn_mfma_f32_16x16x32_bf16(ahi, wh, acc, 0, 0, 0);
  acc = __builtin_amdgcn_mfma_f32_16x16x32_bf16(alo, wh, acc, 0, 0, 0);
  acc = __builtin_amdgcn_mfma_f32_16x16x32_bf16(ahi, wl, acc, 0, 0, 0);
  return acc;
}

// ---------------- single-tile MFMA bilinear core (verified) --------------------
// L0M: 9-dim level-0 inputs, rows >=9 read as zero (predicated; no pad row).
template <int KTN, bool L0M>
__device__ __forceinline__ f32x4 mfma_core(const float* Lcol, const float* Rcol,
                                           const int ld, const ushort* __restrict__ Wf,
                                           int lane) {
  const int g = lane >> 4;
  const int j0 = (g & 1) * 8, gh = g >> 1;
  const float* Lg = Lcol + gh * ld;
  float lf[KTN];
#pragma unroll
  for (int i = 0; i < KTN; ++i)
    lf[i] = (L0M && (2 * i + gh > 8)) ? 0.f : Lg[2 * i * ld];
  f32x2 rf2[4];
#pragma unroll
  for (int j = 0; j < 8; ++j) {
    float v = (L0M && (j0 + j >= 9)) ? 0.f : Rcol[(j0 + j) * ld];
    rf2[j >> 1][j & 1] = v;
  }
  f32x4 acc = {0.f, 0.f, 0.f, 0.f};
  const int entries = KTN * 512;
#pragma unroll
  for (int kt = 0; kt < KTN; ++kt) {
    const s16x8 wh = *(const s16x8*)&Wf[(kt * 64 + lane) * 8];
    const s16x8 wl = *(const s16x8*)&Wf[entries + (kt * 64 + lane) * 8];
    acc = split3(lf[kt], rf2, wh, wl, acc);
  }
  return acc;
}

#define LDF 67   // front leading dim: 67 % 32 = 3 -> <=2-way LDS conflicts (free)

__device__ __forceinline__ void feats_col(float xv, float* Fb, int col) {
  float s1 = __sinf(xv), c1 = __cosf(xv);
  Fb[0 * LDF + col] = 1.f; Fb[1 * LDF + col] = s1; Fb[5 * LDF + col] = c1;
  float sk = s1, ck = c1;
#pragma unroll
  for (int k = 2; k <= 4; ++k) {
    float sn = s1 * ck + c1 * sk, cn = c1 * ck - s1 * sk;
    sk = sn; ck = cn;
    Fb[k * LDF + col] = sk; Fb[(4 + k) * LDF + col] = ck;
  }
}

// ---------------- Levels 0-3 fused, zero-barrier (R7/R10 best shape) -----------
__global__ __launch_bounds__(256, 4) void ttn_front_kernel(
    const float* __restrict__ x, const float* __restrict__ fminp,
    const ushort* __restrict__ U, float* __restrict__ s1out) {
  __shared__ float F0[9 * LDF], F1[9 * LDF];
  __shared__ float A0[16 * LDF], B0[16 * LDF];
  __shared__ float A1[16 * LDF], B1[16 * LDF];
  __shared__ float A2[16 * LDF], B2[16 * LDF];

  const int tid = threadIdx.x;
  const int lane = tid & 63, w = tid >> 6;
  const int m = lane & 15, g = lane >> 4;
  const int bl = w * 16 + m;
  const int b0 = blockIdx.x * 64;
  const int s = blockIdx.y;
  const float fmin = fminp[0];

  const float* xw = x + (size_t)(b0 + w * 16 + (lane & 15)) * 256 + s * 16;
  float* outG = s1out + (size_t)(s * 16) * BTOT + b0;

  auto storeL = [&](f32x4 a, float* Out) {
#pragma unroll
    for (int r = 0; r < 4; ++r) Out[m * LDF + w * 16 + g * 4 + r] = a[r];
  };

  for (int t = 0; t < 8; ++t) {
    if (lane < 32) {
      int side = lane >> 4;
      float xv = xw[2 * t + side] * fmin;
      feats_col(xv, side ? F1 : F0, w * 16 + (lane & 15));
    }
    f32x4 a = mfma_core<5, true>(&F0[bl], &F1[bl], LDF,
                                 U + OFF0 + (size_t)(8 * s + t) * 5120, lane);
    storeL(a, (t & 1) ? B0 : A0);
    if (t & 1) {
      f32x4 c1 = mfma_core<8, false>(&A0[bl], &B0[bl], LDF,
                                     U + OFF1 + (size_t)(4 * s + (t >> 1)) * 8192, lane);
      storeL(c1, ((t >> 1) & 1) ? B1 : A1);
      if ((t & 3) == 3) {
        f32x4 c2 = mfma_core<8, false>(&A1[bl], &B1[bl], LDF,
                                       U + OFF2 + (size_t)(2 * s + (t >> 2)) * 8192, lane);
        storeL(c2, ((t >> 2) & 1) ? B2 : A2);
        if (t == 7) {
          f32x4 c3 = mfma_core<8, false>(&A2[bl], &B2[bl], LDF,
                                         U + OFF3 + (size_t)s * 8192, lane);
#pragma unroll
          for (int r = 0; r < 4; ++r)
            outG[(size_t)m * BTOT + w * 16 + g * 4 + r] = c3[r];
        }
      }
    }
  }
}

// ---------------- Levels 4-7: tree-parallel, 8 waves / 16-b tile ---------------
// Wave v: L4 node v; barrier; waves 0-3: L5; barrier; 0-1: L6; barrier; 0: L7.
// Serial depth 4 mfma_cores (vs 8 in R7-back). LDS: T (staging, dead after L4
// reads -> reused for L5 out) + P (L4 out, dead after L5 reads -> L6 out).
__global__ __launch_bounds__(512) void ttn_back_kernel(
    const float* __restrict__ s1, const ushort* __restrict__ U,
    float* __restrict__ out) {
  __shared__ float T[256 * 17];        // 17.4 KB
  __shared__ float P[8][16 * 17];      // 8.7 KB
  const int tid = threadIdx.x;
  const int lane = tid & 63, v = tid >> 6;   // v = 0..7
  const int m = lane & 15, g = lane >> 4;
  const int b0 = blockIdx.x * 16;

  auto storeC = [&](f32x4 a, float* Buf) {
#pragma unroll
    for (int r = 0; r < 4; ++r) Buf[m * 17 + g * 4 + r] = a[r];
  };

#pragma unroll
  for (int it = 0; it < 2; ++it) {     // stage [256 rows][16 b], coalesced float4
    int idx = it * 512 + tid;          // 0..1023
    int r = idx >> 2, c4 = (idx & 3) * 4;
    float4 vv = *(const float4*)&s1[(size_t)r * BTOT + b0 + c4];
    T[r * 17 + c4 + 0] = vv.x; T[r * 17 + c4 + 1] = vv.y;
    T[r * 17 + c4 + 2] = vv.z; T[r * 17 + c4 + 3] = vv.w;
  }
  __syncthreads();

  // L4 node v: rows 32v..+15 x 32v+16..+31 -> P[v]
  {
    f32x4 a = mfma_core<8, false>(&T[(32 * v) * 17 + m], &T[(32 * v + 16) * 17 + m],
                                  17, U + OFF4 + (size_t)v * 8192, lane);
    storeC(a, P[v]);
  }
  __syncthreads();

  if (v < 4) {  // L5 node v: P[2v] x P[2v+1] -> T region v (T dead)
    f32x4 a = mfma_core<8, false>(&P[2 * v][m], &P[2 * v + 1][m], 17,
                                  U + OFF5 + (size_t)v * 8192, lane);
    storeC(a, &T[v * 16 * 17]);
  }
  __syncthreads();

  if (v < 2) {  // L6 node v: Tq[2v] x Tq[2v+1] -> P[v] (P dead)
    f32x4 a = mfma_core<8, false>(&T[(2 * v) * 16 * 17 + m],
                                  &T[(2 * v + 1) * 16 * 17 + m], 17,
                                  U + OFF6 + (size_t)v * 8192, lane);
    storeC(a, P[v]);
  }
  __syncthreads();

  if (v == 0) { // L7: P[0] x P[1]; W7-frag nonzero only in d=0 column
    f32x4 a = mfma_core<8, false>(&P[0][m], &P[1][m], 17, U + OFF7, lane);
    if (m == 0) {
#pragma unroll
      for (int r = 0; r < 4; ++r) out[b0 + g * 4 + r] = a[r];
    }
  }
}

extern "C" void kernel_launch(void* const* d_in, const int* in_sizes, int n_in,
                              void* d_out, int out_size, void* d_ws, size_t ws_size,
                              hipStream_t stream) {
  const float* x    = (const float*)d_in[0];
  const float* fmin = (const float*)d_in[1];
  const float* W0   = (const float*)d_in[2];
  const float* W1   = (const float*)d_in[3];
  const float* W2   = (const float*)d_in[4];
  const float* W3   = (const float*)d_in[5];
  const float* W4   = (const float*)d_in[6];
  const float* W5   = (const float*)d_in[7];
  const float* W6   = (const float*)d_in[8];
  const float* W7   = (const float*)d_in[9];
  float* out = (float*)d_out;

  // ws: [0,4MB) W-frags U | [4MB,+16.8MB) s1
  ushort* U = (ushort*)d_ws;
  float* s1 = (float*)((char*)d_ws + (4u << 20));

  wprep_kernel<<<255, 256, 0, stream>>>(W0, W1, W2, W3, W4, W5, W6, W7, U);
  ttn_front_kernel<<<dim3(256, 16), 256, 0, stream>>>(x, fmin, U, s1);
  ttn_back_kernel<<<1024, 512, 0, stream>>>(s1, U, out);
}

// Round 14
// 234.552 us; speedup vs baseline: 1.3310x; 1.0034x over previous
//
#include <hip/hip_runtime.h>
#include <math.h>

#define BTOT 16384

typedef __attribute__((ext_vector_type(8))) short s16x8;
typedef __attribute__((ext_vector_type(4))) float f32x4;
typedef __attribute__((ext_vector_type(4))) uint u32x4;
typedef __attribute__((ext_vector_type(2))) float f32x2;
typedef __attribute__((ext_vector_type(2))) uint u32x2;

// U region offsets (in ushorts). Per-node blob: [KTN*512 hi][KTN*512 lo].
#define OFF0 0u          // W0: 128 nodes x 5120
#define OFF1 655360u     // W1: 64 x 8192
#define OFF2 1179648u    // W2: 32 x 8192
#define OFF3 1441792u    // W3: 16 x 8192
#define OFF4 1572864u    // W4: 8 x 8192
#define OFF5 1638400u    // W5: 4 x 8192
#define OFF6 1671168u    // W6: 2 x 8192
#define OFF7 1687552u    // W7: 1 x 8192

__device__ __forceinline__ ushort rtn_bf16(float x) {
  uint u = __builtin_bit_cast(uint, x);
  uint r = u + 0x7fffu + ((u >> 16) & 1u);
  return (ushort)(r >> 16);
}

// ---------------- W-frag prep: LDS-staged coalesced reads ----------------------
__global__ __launch_bounds__(256) void wprep_kernel(
    const float* __restrict__ W0, const float* __restrict__ W1,
    const float* __restrict__ W2, const float* __restrict__ W3,
    const float* __restrict__ W4, const float* __restrict__ W5,
    const float* __restrict__ W6, const float* __restrict__ W7,
    ushort* __restrict__ U) {
  __shared__ float WL[4096];
  int blk = blockIdx.x;
  const float* Wsrc; ushort* dst; int ktN, din, nsrc; bool dout1 = false;
  if (blk < 128)      { Wsrc = W0 + blk * 1296;         dst = U + OFF0 + (size_t)blk * 5120;         ktN = 5; din = 9;  nsrc = 1296; }
  else if (blk < 192) { Wsrc = W1 + (blk - 128) * 4096; dst = U + OFF1 + (size_t)(blk - 128) * 8192; ktN = 8; din = 16; nsrc = 4096; }
  else if (blk < 224) { Wsrc = W2 + (blk - 192) * 4096; dst = U + OFF2 + (size_t)(blk - 192) * 8192; ktN = 8; din = 16; nsrc = 4096; }
  else if (blk < 240) { Wsrc = W3 + (blk - 224) * 4096; dst = U + OFF3 + (size_t)(blk - 224) * 8192; ktN = 8; din = 16; nsrc = 4096; }
  else if (blk < 248) { Wsrc = W4 + (blk - 240) * 4096; dst = U + OFF4 + (size_t)(blk - 240) * 8192; ktN = 8; din = 16; nsrc = 4096; }
  else if (blk < 252) { Wsrc = W5 + (blk - 248) * 4096; dst = U + OFF5 + (size_t)(blk - 248) * 8192; ktN = 8; din = 16; nsrc = 4096; }
  else if (blk < 254) { Wsrc = W6 + (blk - 252) * 4096; dst = U + OFF6 + (size_t)(blk - 252) * 8192; ktN = 8; din = 16; nsrc = 4096; }
  else                { Wsrc = W7;                      dst = U + OFF7;                              ktN = 8; din = 16; nsrc = 256; dout1 = true; }
  for (int i = threadIdx.x; i < nsrc; i += 256) WL[i] = Wsrc[i];   // coalesced
  __syncthreads();
  int entries = ktN * 512;
  for (int e = threadIdx.x; e < entries; e += 256) {
    int kt = e >> 9, l = (e >> 3) & 63, jv = e & 7;
    int k = kt * 32 + ((l >> 4) << 3) + jv;
    int i = k >> 4, j = k & 15, n = l & 15;
    float w;
    if (dout1) w = (n == 0) ? WL[i * 16 + j] : 0.f;
    else       w = (i < din && j < din) ? WL[(i * din + j) * 16 + n] : 0.f;
    uint u = __builtin_bit_cast(uint, w);
    uint h = u & 0xffff0000u;
    dst[e] = (ushort)(h >> 16);
    dst[entries + e] = rtn_bf16(w - __builtin_bit_cast(float, h));
  }
}

// ---- split + 3 MFMAs for one 16-b tile, given resident wh/wl ------------------
__device__ __forceinline__ f32x4 split3(float li, const f32x2* rf2,
                                        s16x8 wh, s16x8 wl, f32x4 acc) {
  const f32x2 li2 = {li, li};
  u32x4 hv, lv;
#pragma unroll
  for (int jp = 0; jp < 4; ++jp) {
    f32x2 p2 = li2 * rf2[jp];
    u32x2 u2 = __builtin_bit_cast(u32x2, p2);
    u32x2 hb = u2 & 0xffff0000u;
    f32x2 h2 = __builtin_bit_cast(f32x2, hb);
    f32x2 q2 = __builtin_elementwise_fma(li2, rf2[jp], -h2);
    u32x2 uq = __builtin_bit_cast(u32x2, q2);
    hv[jp] = __builtin_amdgcn_perm(u2.y, u2.x, 0x07060302u);
    lv[jp] = __builtin_amdgcn_perm(uq.y, uq.x, 0x07060302u);
  }
  s16x8 ahi = __builtin_bit_cast(s16x8, hv);
  s16x8 alo = __builtin_bit_cast(s16x8, lv);
  acc = __builtin_amdgcn_mfma_f32_16x16x32_bf16(ahi, wh, acc, 0, 0, 0);
  acc = __builtin_amdgcn_mfma_f32_16x16x32_bf16(alo, wh, acc, 0, 0, 0);
  acc = __builtin_amdgcn_mfma_f32_16x16x32_bf16(ahi, wl, acc, 0, 0, 0);
  return acc;
}

// ---------------- single-tile MFMA bilinear core (verified) --------------------
// L0M: 9-dim level-0 inputs, rows >=9 read as zero (predicated; no pad row).
template <int KTN, bool L0M>
__device__ __forceinline__ f32x4 mfma_core(const float* Lcol, const float* Rcol,
                                           const int ld, const ushort* __restrict__ Wf,
                                           int lane) {
  const int g = lane >> 4;
  const int j0 = (g & 1) * 8, gh = g >> 1;
  const float* Lg = Lcol + gh * ld;
  float lf[KTN];
#pragma unroll
  for (int i = 0; i < KTN; ++i)
    lf[i] = (L0M && (2 * i + gh > 8)) ? 0.f : Lg[2 * i * ld];
  f32x2 rf2[4];
#pragma unroll
  for (int j = 0; j < 8; ++j) {
    float v = (L0M && (j0 + j >= 9)) ? 0.f : Rcol[(j0 + j) * ld];
    rf2[j >> 1][j & 1] = v;
  }
  f32x4 acc = {0.f, 0.f, 0.f, 0.f};
  const int entries = KTN * 512;
#pragma unroll
  for (int kt = 0; kt < KTN; ++kt) {
    const s16x8 wh = *(const s16x8*)&Wf[(kt * 64 + lane) * 8];
    const s16x8 wl = *(const s16x8*)&Wf[entries + (kt * 64 + lane) * 8];
    acc = split3(lf[kt], rf2, wh, wl, acc);
  }
  return acc;
}

#define LDF 67   // front leading dim: 67 % 32 = 3 -> <=2-way LDS conflicts (free)

__device__ __forceinline__ void feats_col(float xv, float* Fb, int col) {
  float s1 = __sinf(xv), c1 = __cosf(xv);
  Fb[0 * LDF + col] = 1.f; Fb[1 * LDF + col] = s1; Fb[5 * LDF + col] = c1;
  float sk = s1, ck = c1;
#pragma unroll
  for (int k = 2; k <= 4; ++k) {
    float sn = s1 * ck + c1 * sk, cn = c1 * ck - s1 * sk;
    sk = sn; ck = cn;
    Fb[k * LDF + col] = sk; Fb[(4 + k) * LDF + col] = ck;
  }
}

// ---------------- Levels 0-3 fused, zero-barrier (R7/R10 best shape) -----------
__global__ __launch_bounds__(256, 4) void ttn_front_kernel(
    const float* __restrict__ x, const float* __restrict__ fminp,
    const ushort* __restrict__ U, float* __restrict__ s1out) {
  __shared__ float F0[9 * LDF], F1[9 * LDF];
  __shared__ float A0[16 * LDF], B0[16 * LDF];
  __shared__ float A1[16 * LDF], B1[16 * LDF];
  __shared__ float A2[16 * LDF], B2[16 * LDF];

  const int tid = threadIdx.x;
  const int lane = tid & 63, w = tid >> 6;
  const int m = lane & 15, g = lane >> 4;
  const int bl = w * 16 + m;
  const int b0 = blockIdx.x * 64;
  const int s = blockIdx.y;
  const float fmin = fminp[0];

  const float* xw = x + (size_t)(b0 + w * 16 + (lane & 15)) * 256 + s * 16;
  float* outG = s1out + (size_t)(s * 16) * BTOT + b0;

  auto storeL = [&](f32x4 a, float* Out) {
#pragma unroll
    for (int r = 0; r < 4; ++r) Out[m * LDF + w * 16 + g * 4 + r] = a[r];
  };

  for (int t = 0; t < 8; ++t) {
    if (lane < 32) {
      int side = lane >> 4;
      float xv = xw[2 * t + side] * fmin;
      feats_col(xv, side ? F1 : F0, w * 16 + (lane & 15));
    }
    f32x4 a = mfma_core<5, true>(&F0[bl], &F1[bl], LDF,
                                 U + OFF0 + (size_t)(8 * s + t) * 5120, lane);
    storeL(a, (t & 1) ? B0 : A0);
    if (t & 1) {
      f32x4 c1 = mfma_core<8, false>(&A0[bl], &B0[bl], LDF,
                                     U + OFF1 + (size_t)(4 * s + (t >> 1)) * 8192, lane);
      storeL(c1, ((t >> 1) & 1) ? B1 : A1);
      if ((t & 3) == 3) {
        f32x4 c2 = mfma_core<8, false>(&A1[bl], &B1[bl], LDF,
                                       U + OFF2 + (size_t)(2 * s + (t >> 2)) * 8192, lane);
        storeL(c2, ((t >> 2) & 1) ? B2 : A2);
        if (t == 7) {
          f32x4 c3 = mfma_core<8, false>(&A2[bl], &B2[bl], LDF,
                                         U + OFF3 + (size_t)s * 8192, lane);
#pragma unroll
          for (int r = 0; r < 4; ++r)
            outG[(size_t)m * BTOT + w * 16 + g * 4 + r] = c3[r];
        }
      }
    }
  }
}

// ---------------- Levels 4-7: tree-parallel, 8 waves / 16-b tile ---------------
// Wave v: L4 node v; barrier; waves 0-3: L5; barrier; 0-1: L6; barrier; 0: L7.
// Serial depth 4 mfma_cores (vs 8 in R7-back). LDS: T (staging, dead after L4
// reads -> reused for L5 out) + P (L4 out, dead after L5 reads -> L6 out).
__global__ __launch_bounds__(512) void ttn_back_kernel(
    const float* __restrict__ s1, const ushort* __restrict__ U,
    float* __restrict__ out) {
  __shared__ float T[256 * 17];        // 17.4 KB
  __shared__ float P[8][16 * 17];      // 8.7 KB
  const int tid = threadIdx.x;
  const int lane = tid & 63, v = tid >> 6;   // v = 0..7
  const int m = lane & 15, g = lane >> 4;
  const int b0 = blockIdx.x * 16;

  auto storeC = [&](f32x4 a, float* Buf) {
#pragma unroll
    for (int r = 0; r < 4; ++r) Buf[m * 17 + g * 4 + r] = a[r];
  };

#pragma unroll
  for (int it = 0; it < 2; ++it) {     // stage [256 rows][16 b], coalesced float4
    int idx = it * 512 + tid;          // 0..1023
    int r = idx >> 2, c4 = (idx & 3) * 4;
    float4 vv = *(const float4*)&s1[(size_t)r * BTOT + b0 + c4];
    T[r * 17 + c4 + 0] = vv.x; T[r * 17 + c4 + 1] = vv.y;
    T[r * 17 + c4 + 2] = vv.z; T[r * 17 + c4 + 3] = vv.w;
  }
  __syncthreads();

  // L4 node v: rows 32v..+15 x 32v+16..+31 -> P[v]
  {
    f32x4 a = mfma_core<8, false>(&T[(32 * v) * 17 + m], &T[(32 * v + 16) * 17 + m],
                                  17, U + OFF4 + (size_t)v * 8192, lane);
    storeC(a, P[v]);
  }
  __syncthreads();

  if (v < 4) {  // L5 node v: P[2v] x P[2v+1] -> T region v (T dead)
    f32x4 a = mfma_core<8, false>(&P[2 * v][m], &P[2 * v + 1][m], 17,
                                  U + OFF5 + (size_t)v * 8192, lane);
    storeC(a, &T[v * 16 * 17]);
  }
  __syncthreads();

  if (v < 2) {  // L6 node v: Tq[2v] x Tq[2v+1] -> P[v] (P dead)
    f32x4 a = mfma_core<8, false>(&T[(2 * v) * 16 * 17 + m],
                                  &T[(2 * v + 1) * 16 * 17 + m], 17,
                                  U + OFF6 + (size_t)v * 8192, lane);
    storeC(a, P[v]);
  }
  __syncthreads();

  if (v == 0) { // L7: P[0] x P[1]; W7-frag nonzero only in d=0 column
    f32x4 a = mfma_core<8, false>(&P[0][m], &P[1][m], 17, U + OFF7, lane);
    if (m == 0) {
#pragma unroll
      for (int r = 0; r < 4; ++r) out[b0 + g * 4 + r] = a[r];
    }
  }
}

extern "C" void kernel_launch(void* const* d_in, const int* in_sizes, int n_in,
                              void* d_out, int out_size, void* d_ws, size_t ws_size,
                              hipStream_t stream) {
  const float* x    = (const float*)d_in[0];
  const float* fmin = (const float*)d_in[1];
  const float* W0   = (const float*)d_in[2];
  const float* W1   = (const float*)d_in[3];
  const float* W2   = (const float*)d_in[4];
  const float* W3   = (const float*)d_in[5];
  const float* W4   = (const float*)d_in[6];
  const float* W5   = (const float*)d_in[7];
  const float* W6   = (const float*)d_in[8];
  const float* W7   = (const float*)d_in[9];
  float* out = (float*)d_out;

  // ws: [0,4MB) W-frags U | [4MB,+16.8MB) s1
  ushort* U = (ushort*)d_ws;
  float* s1 = (float*)((char*)d_ws + (4u << 20));

  wprep_kernel<<<255, 256, 0, stream>>>(W0, W1, W2, W3, W4, W5, W6, W7, U);
  ttn_front_kernel<<<dim3(256, 16), 256, 0, stream>>>(x, fmin, U, s1);
  ttn_back_kernel<<<1024, 512, 0, stream>>>(s1, U, out);
}

// Round 16
// 233.768 us; speedup vs baseline: 1.3354x; 1.0034x over previous
//
#include <hip/hip_runtime.h>
#include <math.h>

#define BTOT 16384

typedef __attribute__((ext_vector_type(8))) short s16x8;
typedef __attribute__((ext_vector_type(4))) float f32x4;
typedef __attribute__((ext_vector_type(4))) uint u32x4;
typedef __attribute__((ext_vector_type(2))) float f32x2;
typedef __attribute__((ext_vector_type(2))) uint u32x2;

// U region offsets (in ushorts). Per-node blob: [KTN*512 hi][KTN*512 lo].
#define OFF0 0u          // W0: 128 nodes x 5120
#define OFF1 655360u     // W1: 64 x 8192
#define OFF2 1179648u    // W2: 32 x 8192
#define OFF3 1441792u    // W3: 16 x 8192
#define OFF4 1572864u    // W4: 8 x 8192
#define OFF5 1638400u    // W5: 4 x 8192
#define OFF6 1671168u    // W6: 2 x 8192
#define OFF7 1687552u    // W7: 1 x 8192

__device__ __forceinline__ ushort rtn_bf16(float x) {
  uint u = __builtin_bit_cast(uint, x);
  uint r = u + 0x7fffu + ((u >> 16) & 1u);
  return (ushort)(r >> 16);
}

// ---------------- W-frag prep: LDS-staged coalesced reads ----------------------
__global__ __launch_bounds__(256) void wprep_kernel(
    const float* __restrict__ W0, const float* __restrict__ W1,
    const float* __restrict__ W2, const float* __restrict__ W3,
    const float* __restrict__ W4, const float* __restrict__ W5,
    const float* __restrict__ W6, const float* __restrict__ W7,
    ushort* __restrict__ U) {
  __shared__ float WL[4096];
  int blk = blockIdx.x;
  const float* Wsrc; ushort* dst; int ktN, din, nsrc; bool dout1 = false;
  if (blk < 128)      { Wsrc = W0 + blk * 1296;         dst = U + OFF0 + (size_t)blk * 5120;         ktN = 5; din = 9;  nsrc = 1296; }
  else if (blk < 192) { Wsrc = W1 + (blk - 128) * 4096; dst = U + OFF1 + (size_t)(blk - 128) * 8192; ktN = 8; din = 16; nsrc = 4096; }
  else if (blk < 224) { Wsrc = W2 + (blk - 192) * 4096; dst = U + OFF2 + (size_t)(blk - 192) * 8192; ktN = 8; din = 16; nsrc = 4096; }
  else if (blk < 240) { Wsrc = W3 + (blk - 224) * 4096; dst = U + OFF3 + (size_t)(blk - 224) * 8192; ktN = 8; din = 16; nsrc = 4096; }
  else if (blk < 248) { Wsrc = W4 + (blk - 240) * 4096; dst = U + OFF4 + (size_t)(blk - 240) * 8192; ktN = 8; din = 16; nsrc = 4096; }
  else if (blk < 252) { Wsrc = W5 + (blk - 248) * 4096; dst = U + OFF5 + (size_t)(blk - 248) * 8192; ktN = 8; din = 16; nsrc = 4096; }
  else if (blk < 254) { Wsrc = W6 + (blk - 252) * 4096; dst = U + OFF6 + (size_t)(blk - 252) * 8192; ktN = 8; din = 16; nsrc = 4096; }
  else                { Wsrc = W7;                      dst = U + OFF7;                              ktN = 8; din = 16; nsrc = 256; dout1 = true; }
  for (int i = threadIdx.x; i < nsrc; i += 256) WL[i] = Wsrc[i];   // coalesced
  __syncthreads();
  int entries = ktN * 512;
  for (int e = threadIdx.x; e < entries; e += 256) {
    int kt = e >> 9, l = (e >> 3) & 63, jv = e & 7;
    int k = kt * 32 + ((l >> 4) << 3) + jv;
    int i = k >> 4, j = k & 15, n = l & 15;
    float w;
    if (dout1) w = (n == 0) ? WL[i * 16 + j] : 0.f;
    else       w = (i < din && j < din) ? WL[(i * din + j) * 16 + n] : 0.f;
    uint u = __builtin_bit_cast(uint, w);
    uint h = u & 0xffff0000u;
    dst[e] = (ushort)(h >> 16);
    dst[entries + e] = rtn_bf16(w - __builtin_bit_cast(float, h));
  }
}

// ---- split + 3 MFMAs for one 16-b tile, given resident wh/wl ------------------
__device__ __forceinline__ f32x4 split3(float li, const f32x2* rf2,
                                        s16x8 wh, s16x8 wl, f32x4 acc) {
  const f32x2 li2 = {li, li};
  u32x4 hv, lv;
#pragma unroll
  for (int jp = 0; jp < 4; ++jp) {
    f32x2 p2 = li2 * rf2[jp];
    u32x2 u2 = __builtin_bit_cast(u32x2, p2);
    u32x2 hb = u2 & 0xffff0000u;
    f32x2 h2 = __builtin_bit_cast(f32x2, hb);
    f32x2 q2 = __builtin_elementwise_fma(li2, rf2[jp], -h2);
    u32x2 uq = __builtin_bit_cast(u32x2, q2);
    hv[jp] = __builtin_amdgcn_perm(u2.y, u2.x, 0x07060302u);
    lv[jp] = __builtin_amdgcn_perm(uq.y, uq.x, 0x07060302u);
  }
  s16x8 ahi = __builtin_bit_cast(s16x8, hv);
  s16x8 alo = __builtin_bit_cast(s16x8, lv);
  acc = __builtin_amdgcn_mfma_f32_16x16x32_bf16(ahi, wh, acc, 0, 0, 0);
  acc = __builtin_amdgcn_mfma_f32_16x16x32_bf16(alo, wh, acc, 0, 0, 0);
  acc = __builtin_amdgcn_mfma_f32_16x16x32_bf16(ahi, wl, acc, 0, 0, 0);
  return acc;
}

// ---------------- single-tile MFMA bilinear core (verified) --------------------
// L0M: 9-dim level-0 inputs, rows >=9 read as zero (predicated; no pad row).
template <int KTN, bool L0M>
__device__ __forceinline__ f32x4 mfma_core(const float* Lcol, const float* Rcol,
                                           const int ld, const ushort* __restrict__ Wf,
                                           int lane) {
  const int g = lane >> 4;
  const int j0 = (g & 1) * 8, gh = g >> 1;
  const float* Lg = Lcol + gh * ld;
  float lf[KTN];
#pragma unroll
  for (int i = 0; i < KTN; ++i)
    lf[i] = (L0M && (2 * i + gh > 8)) ? 0.f : Lg[2 * i * ld];
  f32x2 rf2[4];
#pragma unroll
  for (int j = 0; j < 8; ++j) {
    float v = (L0M && (j0 + j >= 9)) ? 0.f : Rcol[(j0 + j) * ld];
    rf2[j >> 1][j & 1] = v;
  }
  f32x4 acc = {0.f, 0.f, 0.f, 0.f};
  const int entries = KTN * 512;
#pragma unroll
  for (int kt = 0; kt < KTN; ++kt) {
    const s16x8 wh = *(const s16x8*)&Wf[(kt * 64 + lane) * 8];
    const s16x8 wl = *(const s16x8*)&Wf[entries + (kt * 64 + lane) * 8];
    acc = split3(lf[kt], rf2, wh, wl, acc);
  }
  return acc;
}

#define LDF 67   // front leading dim: 67 % 32 = 3 -> <=2-way LDS conflicts (free)

__device__ __forceinline__ void feats_col(float xv, float* Fb, int col) {
  float s1 = __sinf(xv), c1 = __cosf(xv);
  Fb[0 * LDF + col] = 1.f; Fb[1 * LDF + col] = s1; Fb[5 * LDF + col] = c1;
  float sk = s1, ck = c1;
#pragma unroll
  for (int k = 2; k <= 4; ++k) {
    float sn = s1 * ck + c1 * sk, cn = c1 * ck - s1 * sk;
    sk = sn; ck = cn;
    Fb[k * LDF + col] = sk; Fb[(4 + k) * LDF + col] = ck;
  }
}

// ---------------- Levels 0-3 fused, zero-barrier (R7/R10 best shape) -----------
__global__ __launch_bounds__(256, 4) void ttn_front_kernel(
    const float* __restrict__ x, const float* __restrict__ fminp,
    const ushort* __restrict__ U, float* __restrict__ s1out) {
  __shared__ float F0[9 * LDF], F1[9 * LDF];
  __shared__ float A0[16 * LDF], B0[16 * LDF];
  __shared__ float A1[16 * LDF], B1[16 * LDF];
  __shared__ float A2[16 * LDF], B2[16 * LDF];

  const int tid = threadIdx.x;
  const int lane = tid & 63, w = tid >> 6;
  const int m = lane & 15, g = lane >> 4;
  const int bl = w * 16 + m;
  const int b0 = blockIdx.x * 64;
  const int s = blockIdx.y;
  const float fmin = fminp[0];

  const float* xw = x + (size_t)(b0 + w * 16 + (lane & 15)) * 256 + s * 16;
  float* outG = s1out + (size_t)(s * 16) * BTOT + b0;

  auto storeL = [&](f32x4 a, float* Out) {
#pragma unroll
    for (int r = 0; r < 4; ++r) Out[m * LDF + w * 16 + g * 4 + r] = a[r];
  };

  for (int t = 0; t < 8; ++t) {
    if (lane < 32) {
      int side = lane >> 4;
      float xv = xw[2 * t + side] * fmin;
      feats_col(xv, side ? F1 : F0, w * 16 + (lane & 15));
    }
    f32x4 a = mfma_core<5, true>(&F0[bl], &F1[bl], LDF,
                                 U + OFF0 + (size_t)(8 * s + t) * 5120, lane);
    storeL(a, (t & 1) ? B0 : A0);
    if (t & 1) {
      f32x4 c1 = mfma_core<8, false>(&A0[bl], &B0[bl], LDF,
                                     U + OFF1 + (size_t)(4 * s + (t >> 1)) * 8192, lane);
      storeL(c1, ((t >> 1) & 1) ? B1 : A1);
      if ((t & 3) == 3) {
        f32x4 c2 = mfma_core<8, false>(&A1[bl], &B1[bl], LDF,
                                       U + OFF2 + (size_t)(2 * s + (t >> 2)) * 8192, lane);
        storeL(c2, ((t >> 2) & 1) ? B2 : A2);
        if (t == 7) {
          f32x4 c3 = mfma_core<8, false>(&A2[bl], &B2[bl], LDF,
                                         U + OFF3 + (size_t)s * 8192, lane);
#pragma unroll
          for (int r = 0; r < 4; ++r)
            outG[(size_t)m * BTOT + w * 16 + g * 4 + r] = c3[r];
        }
      }
    }
  }
}

// ---------------- Levels 4-7: tree-parallel, 8 waves / 16-b tile ---------------
// Wave v: L4 node v; barrier; waves 0-3: L5; barrier; 0-1: L6; barrier; 0: L7.
// Serial depth 4 mfma_cores (vs 8 in R7-back). LDS: T (staging, dead after L4
// reads -> reused for L5 out) + P (L4 out, dead after L5 reads -> L6 out).
__global__ __launch_bounds__(512) void ttn_back_kernel(
    const float* __restrict__ s1, const ushort* __restrict__ U,
    float* __restrict__ out) {
  __shared__ float T[256 * 17];        // 17.4 KB
  __shared__ float P[8][16 * 17];      // 8.7 KB
  const int tid = threadIdx.x;
  const int lane = tid & 63, v = tid >> 6;   // v = 0..7
  const int m = lane & 15, g = lane >> 4;
  const int b0 = blockIdx.x * 16;

  auto storeC = [&](f32x4 a, float* Buf) {
#pragma unroll
    for (int r = 0; r < 4; ++r) Buf[m * 17 + g * 4 + r] = a[r];
  };

#pragma unroll
  for (int it = 0; it < 2; ++it) {     // stage [256 rows][16 b], coalesced float4
    int idx = it * 512 + tid;          // 0..1023
    int r = idx >> 2, c4 = (idx & 3) * 4;
    float4 vv = *(const float4*)&s1[(size_t)r * BTOT + b0 + c4];
    T[r * 17 + c4 + 0] = vv.x; T[r * 17 + c4 + 1] = vv.y;
    T[r * 17 + c4 + 2] = vv.z; T[r * 17 + c4 + 3] = vv.w;
  }
  __syncthreads();

  // L4 node v: rows 32v..+15 x 32v+16..+31 -> P[v]
  {
    f32x4 a = mfma_core<8, false>(&T[(32 * v) * 17 + m], &T[(32 * v + 16) * 17 + m],
                                  17, U + OFF4 + (size_t)v * 8192, lane);
    storeC(a, P[v]);
  }
  __syncthreads();

  if (v < 4) {  // L5 node v: P[2v] x P[2v+1] -> T region v (T dead)
    f32x4 a = mfma_core<8, false>(&P[2 * v][m], &P[2 * v + 1][m], 17,
                                  U + OFF5 + (size_t)v * 8192, lane);
    storeC(a, &T[v * 16 * 17]);
  }
  __syncthreads();

  if (v < 2) {  // L6 node v: Tq[2v] x Tq[2v+1] -> P[v] (P dead)
    f32x4 a = mfma_core<8, false>(&T[(2 * v) * 16 * 17 + m],
                                  &T[(2 * v + 1) * 16 * 17 + m], 17,
                                  U + OFF6 + (size_t)v * 8192, lane);
    storeC(a, P[v]);
  }
  __syncthreads();

  if (v == 0) { // L7: P[0] x P[1]; W7-frag nonzero only in d=0 column
    f32x4 a = mfma_core<8, false>(&P[0][m], &P[1][m], 17, U + OFF7, lane);
    if (m == 0) {
#pragma unroll
      for (int r = 0; r < 4; ++r) out[b0 + g * 4 + r] = a[r];
    }
  }
}

extern "C" void kernel_launch(void* const* d_in, const int* in_sizes, int n_in,
                              void* d_out, int out_size, void* d_ws, size_t ws_size,
                              hipStream_t stream) {
  const float* x    = (const float*)d_in[0];
  const float* fmin = (const float*)d_in[1];
  const float* W0   = (const float*)d_in[2];
  const float* W1   = (const float*)d_in[3];
  const float* W2   = (const float*)d_in[4];
  const float* W3   = (const float*)d_in[5];
  const float* W4   = (const float*)d_in[6];
  const float* W5   = (const float*)d_in[7];
  const float* W6   = (const float*)d_in[8];
  const float* W7   = (const float*)d_in[9];
  float* out = (float*)d_out;

  // ws: [0,4MB) W-frags U | [4MB,+16.8MB) s1
  ushort* U = (ushort*)d_ws;
  float* s1 = (float*)((char*)d_ws + (4u << 20));

  wprep_kernel<<<255, 256, 0, stream>>>(W0, W1, W2, W3, W4, W5, W6, W7, U);
  ttn_front_kernel<<<dim3(256, 16), 256, 0, stream>>>(x, fmin, U, s1);
  ttn_back_kernel<<<1024, 512, 0, stream>>>(s1, U, out);
}